// Round 10
// baseline (285.486 us; speedup 1.0000x reference)
//
#include <hip/hip_runtime.h>
#include <hip/hip_bf16.h>

// ---- problem constants ----
#define OUT_CH   31
#define COEF_LEN 7688                 // 31*31*8
#define NPIX     16384                // 128*128
#define CHUNKS   31                   // KAN input channels (independent param groups)
#define NFRG     24                   // param fragments per chunk (384 padded M rows)
#define NR       9                    // K-steps: r = ky*3+kx; k-in-step = conv channel ci
#define FRAG_U16 512                  // u16 per fragment (64 lanes x 8)
#define BP3_B    ((size_t)CHUNKS*NR*NFRG*FRAG_U16*2)   // 6,856,704
#define BIAS_ELE (CHUNKS*NFRG*16)     // 11904 f32
#define P1_B     ((size_t)OUT_CH*NPIX*4)               // 2,031,616
#define WS_NEED  (BP3_B + (size_t)BIAS_ELE*4 + P1_B)   // 8,935,936

#define SLAB_STRIDE 40                // u16 slots per (row,col): 80 B, 16B-aligned

using f32x4 = __attribute__((ext_vector_type(4))) float;
using s16x8 = __attribute__((ext_vector_type(8))) short;

__device__ __forceinline__ unsigned short f2bf(float f) {
    unsigned int u = __float_as_uint(f);
    unsigned int r = (u + 0x7FFFu + ((u >> 16) & 1u)) >> 16;
    return (unsigned short)r;
}

// ---------------------------------------------------------------------------
// Pack gen_w/gen_b into bf16 A-fragment layout + bias table.
//  bp3[i][r][f][lane][8] bf16.  M-row m = lane&15; k-in-step ci = (lane>>4)*8+jj.
//  param identity: o = (m>>2)*8 + f/3, jslot = (f%3)*4 + (m&3)
//    jslot 0..7 = coef j, 8 = univ, 9 = res, 10..11 = zero pad
//  bias_pk[(i*24+f)*16 + m] f32 = gb[p].
// ---------------------------------------------------------------------------
__global__ void pack_kernel(const float* __restrict__ gw, const float* __restrict__ gb,
                            unsigned short* __restrict__ bp, float* __restrict__ bias_pk) {
    const int NMAIN = CHUNKS * NFRG * 64;          // 47616
    int tt = blockIdx.x * 256 + threadIdx.x;
    if (tt < NMAIN) {
        int lane = tt & 63;
        int u = tt >> 6;
        int f = u % NFRG;
        int i = u / NFRG;
        int m = lane & 15, q8 = lane >> 4;
        int o = (m >> 2) * 8 + f / 3;
        int jslot = (f % 3) * 4 + (m & 3);
        int p = -1;
        if (o < OUT_CH && jslot < 10) {
            if (jslot < 8)       p = i * 248 + o * 8 + jslot;
            else if (jslot == 8) p = COEF_LEN + i * 31 + o;
            else                 p = COEF_LEN + 961 + i * 31 + o;
        }
        s16x8 vr[NR];
        #pragma unroll
        for (int r = 0; r < NR; ++r)
            #pragma unroll
            for (int jj = 0; jj < 8; ++jj) vr[r][jj] = 0;
        #pragma unroll
        for (int jj = 0; jj < 8; ++jj) {
            int ci = q8 * 8 + jj;
            if (p >= 0 && ci < 31) {
                const float* gr = gw + (long)p * 279 + ci * 9;
                #pragma unroll
                for (int r = 0; r < NR; ++r) vr[r][jj] = (short)f2bf(gr[r]);
            }
        }
        #pragma unroll
        for (int r = 0; r < NR; ++r)
            *reinterpret_cast<s16x8*>(bp + (((size_t)i * NR + r) * NFRG + f) * FRAG_U16 + lane * 8) = vr[r];
    } else if (tt < NMAIN + BIAS_ELE) {
        int u = tt - NMAIN;
        int m = u & 15;
        int t2 = u >> 4;
        int f = t2 % NFRG;
        int i = t2 / NFRG;
        int o = (m >> 2) * 8 + f / 3;
        int jslot = (f % 3) * 4 + (m & 3);
        float val = 0.f;
        if (o < OUT_CH && jslot < 10) {
            int p;
            if (jslot < 8)       p = i * 248 + o * 8 + jslot;
            else if (jslot == 8) p = COEF_LEN + i * 31 + o;
            else                 p = COEF_LEN + 961 + i * 31 + o;
            val = gb[p];
        }
        bias_pk[u] = val;
    }
}

// ---------------------------------------------------------------------------
// Fused conv-GEMM + KAN epilogue. A-fragments stream GLOBAL -> VGPR (each
// frag consumed by exactly one wave: WM=8, WP=1 -> zero duplication, no LDS
// round-trip, compiler-managed register deps = structurally race-free).
// LDS holds only the read-only x slab + bias; ONE __syncthreads total.
// Grid 256 = 128 rows x 2 chunk-groups, 1 block/CU (VGPR ~200 -> 2 waves/SIMD).
// Per step: prefetch pa[(r+1)&1] (static idx, unrolled) -> 8 pbv ds_reads ->
// 24 MFMA. LDS traffic = B only (64 KB/step vs R8's 104). acc[3][8]=96 VGPR.
// Output: cg0 -> out, cg1 -> ws partial (+reduce); chained fallback if ws small.
// ---------------------------------------------------------------------------
__global__ void __launch_bounds__(512, 2)
main_kernel(const float* __restrict__ x, const unsigned short* __restrict__ bp3,
            const float* __restrict__ bias_pk, float* __restrict__ dst0,
            float* __restrict__ dst1, int two_cg, int c0_in, int nc_in, int add_in) {
    __shared__ unsigned short slab[3 * 130 * SLAB_STRIDE];   // 31200 B
    __shared__ float biasl[16 * NFRG * 16];                  // 24576 B

    const int tid = threadIdx.x;
    const int bid = blockIdx.x;
    int row, c0, nc, addf;
    float* dst;
    if (two_cg) {
        int cg = bid & 1;
        row = bid >> 1;
        c0 = cg ? 16 : 0;
        nc = cg ? 15 : 16;
        dst = cg ? dst1 : dst0;
        addf = 0;
    } else {
        row = bid; c0 = c0_in; nc = nc_in; dst = dst0; addf = add_in;
    }

    // slab: rows row-1..row+1, cols -1..128, ALL 40 slots written (31..39 = 0)
    for (int idx = tid; idx < 3 * 130 * SLAB_STRIDE; idx += 512) {
        int slot = idx % SLAB_STRIDE;
        int t = idx / SLAB_STRIDE;
        int cc = t % 130;
        int rr = t / 130;
        int hh = row - 1 + rr, ww = cc - 1;
        float v = 0.f;
        if (slot < 31 && (unsigned)hh < 128u && (unsigned)ww < 128u)
            v = x[slot * NPIX + hh * 128 + ww];
        slab[(rr * 130 + cc) * SLAB_STRIDE + slot] = f2bf(v);
    }
    // bias slice -> LDS
    for (int idx = tid; idx < nc * NFRG * 16; idx += 512)
        biasl[idx] = bias_pk[(size_t)c0 * NFRG * 16 + idx];
    __syncthreads();
    // ---- no further barriers; all cross-thread data is read-only below ----

    const int lane = tid & 63;
    const int wave = tid >> 6;       // 0..7: frags [3*wave, 3*wave+3)
    const int q = lane >> 4;
    const int pix16 = lane & 15;

    int sa[8];
    #pragma unroll
    for (int pg = 0; pg < 8; ++pg)
        sa[pg] = (pg * 16 + pix16) * (SLAB_STRIDE * 2) + q * 16;   // byte offsets

    float oreg[8];
    #pragma unroll
    for (int pg = 0; pg < 8; ++pg) oreg[pg] = 0.f;

    #pragma unroll 1
    for (int k = 0; k < nc; ++k) {
        const int ic = c0 + k;
        // per-chunk A base: frag fl at step r lives at aw + (r*NFRG + fl)*FRAG_U16
        const unsigned short* aw = bp3 + ((size_t)ic * NR * NFRG + wave * 3) * FRAG_U16 + lane * 8;

        // issue r=0 A loads first (fly under acc-init ds_reads)
        s16x8 pa[2][3];
        #pragma unroll
        for (int fl = 0; fl < 3; ++fl)
            pa[0][fl] = *reinterpret_cast<const s16x8*>(aw + fl * FRAG_U16);

        // acc init = bias (LDS broadcast; bias added once, by owning chunk)
        f32x4 acc[3][8];
        const float* bl = biasl + (k * NFRG + wave * 3) * 16 + q * 4;
        #pragma unroll
        for (int fl = 0; fl < 3; ++fl) {
            f32x4 b = *reinterpret_cast<const f32x4*>(bl + fl * 16);
            #pragma unroll
            for (int pg = 0; pg < 8; ++pg) acc[fl][pg] = b;
        }

        #pragma unroll
        for (int r = 0; r < NR; ++r) {
            if (r + 1 < NR) {    // reg-dbuf prefetch; static index (r unrolled)
                #pragma unroll
                for (int fl = 0; fl < 3; ++fl)
                    pa[(r + 1) & 1][fl] = *reinterpret_cast<const s16x8*>(
                        aw + ((r + 1) * NFRG + fl) * FRAG_U16);
            }
            const int roff = ((r / 3) * 130 + (r % 3)) * (SLAB_STRIDE * 2);
            s16x8 pbv[8];
            #pragma unroll
            for (int pg = 0; pg < 8; ++pg)
                pbv[pg] = *reinterpret_cast<const s16x8*>(((const char*)slab) + sa[pg] + roff);

            __builtin_amdgcn_s_setprio(1);
            #pragma unroll
            for (int fl = 0; fl < 3; ++fl)
                #pragma unroll
                for (int pg = 0; pg < 8; ++pg)
                    acc[fl][pg] = __builtin_amdgcn_mfma_f32_16x16x32_bf16(
                        pa[r & 1][fl], pbv[pg], acc[fl][pg], 0, 0, 0);
            __builtin_amdgcn_s_setprio(0);
        }

        // lane-local epilogue: closed-form cubic B-spline + silu residual.
        // lane owns o = q*8 + wave; jslot = fl*4 + reg (fl0-1 coef, fl2 univ/res)
        #pragma unroll
        for (int pg = 0; pg < 8; ++pg) {
            const int wcol = pg * 16 + pix16;
            unsigned short sv = slab[(130 + wcol + 1) * SLAB_STRIDE + ic];
            float xv = __uint_as_float((unsigned)sv << 16);
            float u5 = (xv + 1.0f) * 2.5f;
            float cf = fminf(fmaxf(floorf(u5), 0.f), 4.f);
            int ccb = (int)cf;
            float t = u5 - cf;
            float omt = 1.f - t;
            float t2v = t * t, t3v = t2v * t;
            float bw0 = omt * omt * omt * (1.f / 6.f);
            float bw1 = (3.f * t3v - 6.f * t2v + 4.f) * (1.f / 6.f);
            float bw2 = (-3.f * t3v + 3.f * t2v + 3.f * t + 1.f) * (1.f / 6.f);
            float bw3 = t3v * (1.f / 6.f);
            float sl = xv / (1.f + __expf(-xv));
            float w[8];
            #pragma unroll
            for (int j = 0; j < 8; ++j) {
                float wv = 0.f;
                wv = (j == ccb)     ? bw0 : wv;
                wv = (j == ccb + 1) ? bw1 : wv;
                wv = (j == ccb + 2) ? bw2 : wv;
                wv = (j == ccb + 3) ? bw3 : wv;
                w[j] = wv;
            }
            float sp = 0.f;
            #pragma unroll
            for (int j = 0; j < 8; ++j)
                sp = fmaf(w[j], acc[j >> 2][pg][j & 3], sp);
            oreg[pg] += acc[2][pg][0] * sp + sl * acc[2][pg][1];
        }
    }

    // write: lane's single output channel o = q*8 + wave (o==31 is pad -> skip)
    const int o = q * 8 + wave;
    if (o < OUT_CH) {
        #pragma unroll
        for (int pg = 0; pg < 8; ++pg) {
            size_t gi = (size_t)o * NPIX + row * 128 + pg * 16 + pix16;
            if (addf) dst[gi] += oreg[pg];
            else      dst[gi]  = oreg[pg];
        }
    }
}

__global__ void reduce_kernel(const float* __restrict__ p1, float* __restrict__ out) {
    int e = blockIdx.x * 256 + threadIdx.x;
    if (e < OUT_CH * NPIX) out[e] += p1[e];
}

extern "C" void kernel_launch(void* const* d_in, const int* in_sizes, int n_in,
                              void* d_out, int out_size, void* d_ws, size_t ws_size,
                              hipStream_t stream) {
    const float* x  = (const float*)d_in[0];   // (1,31,128,128)
    const float* gw = (const float*)d_in[1];   // (9610,31,3,3)
    const float* gb = (const float*)d_in[2];   // (9610,)
    float* outp = (float*)d_out;               // (1,31,128,128)
    unsigned short* bpack = (unsigned short*)d_ws;          // 6,856,704 B
    float* bias_pk = (float*)((char*)d_ws + BP3_B);         // + 47,616 B
    float* p1      = (float*)((char*)d_ws + BP3_B + (size_t)BIAS_ELE * 4);

    const int NMAIN = CHUNKS * NFRG * 64;                   // 47616
    int pack_blocks = (NMAIN + BIAS_ELE + 255) / 256;       // 233
    pack_kernel<<<pack_blocks, 256, 0, stream>>>(gw, gb, bpack, bias_pk);

    if (ws_size >= WS_NEED) {
        // single dispatch, both chunk-groups (cg0 -> out, cg1 -> partial), then add
        main_kernel<<<256, 512, 0, stream>>>(x, bpack, bias_pk, outp, p1, 1, 0, 0, 0);
        reduce_kernel<<<(OUT_CH * NPIX + 255) / 256, 256, 0, stream>>>(p1, outp);
    } else {
        // chained fallback: two sequential half-grid dispatches through d_out
        main_kernel<<<128, 512, 0, stream>>>(x, bpack, bias_pk, outp, nullptr, 0, 0, 16, 0);
        main_kernel<<<128, 512, 0, stream>>>(x, bpack, bias_pk, outp, nullptr, 0, 16, 15, 1);
    }
}

// Round 11
// 275.495 us; speedup vs baseline: 1.0363x; 1.0363x over previous
//
#include <hip/hip_runtime.h>
#include <hip/hip_bf16.h>

// ---- problem constants ----
#define OUT_CH   31
#define COEF_LEN 7688                 // 31*31*8
#define NPIX     16384                // 128*128
#define CHUNKS   31                   // KAN input channels (independent param groups)
#define NFRG     24                   // param fragments per chunk (384 padded M rows)
#define NR       9                    // K-steps: r = ky*3+kx; k-in-step = conv channel ci
#define FRAG_U16 512                  // u16 per fragment (64 lanes x 8)
#define BP3_B    ((size_t)CHUNKS*NR*NFRG*FRAG_U16*2)   // 6,856,704
#define BIAS_ELE (CHUNKS*NFRG*16)     // 11904 f32
#define P1_B     ((size_t)OUT_CH*NPIX*4)               // 2,031,616
#define WS_NEED  (BP3_B + (size_t)BIAS_ELE*4 + P1_B)   // 8,935,936

#define SLAB_STRIDE 40                // u16 slots per (row,col): 80 B, 16B-aligned

using f32x4 = __attribute__((ext_vector_type(4))) float;
using s16x8 = __attribute__((ext_vector_type(8))) short;

__device__ __forceinline__ unsigned short f2bf(float f) {
    unsigned int u = __float_as_uint(f);
    unsigned int r = (u + 0x7FFFu + ((u >> 16) & 1u)) >> 16;
    return (unsigned short)r;
}

// ---------------------------------------------------------------------------
// Pack gen_w/gen_b into bf16 A-fragment layout + bias table.
//  bp3[i][r][f][lane][8] bf16.  M-row m = lane&15; k-in-step ci = (lane>>4)*8+jj.
//  param identity: o = (m>>2)*8 + f/3, jslot = (f%3)*4 + (m&3)
//    jslot 0..7 = coef j, 8 = univ, 9 = res, 10..11 = zero pad
//  bias_pk[(i*24+f)*16 + m] f32 = gb[p].
// ---------------------------------------------------------------------------
__global__ void pack_kernel(const float* __restrict__ gw, const float* __restrict__ gb,
                            unsigned short* __restrict__ bp, float* __restrict__ bias_pk) {
    const int NMAIN = CHUNKS * NFRG * 64;          // 47616
    int tt = blockIdx.x * 256 + threadIdx.x;
    if (tt < NMAIN) {
        int lane = tt & 63;
        int u = tt >> 6;
        int f = u % NFRG;
        int i = u / NFRG;
        int m = lane & 15, q8 = lane >> 4;
        int o = (m >> 2) * 8 + f / 3;
        int jslot = (f % 3) * 4 + (m & 3);
        int p = -1;
        if (o < OUT_CH && jslot < 10) {
            if (jslot < 8)       p = i * 248 + o * 8 + jslot;
            else if (jslot == 8) p = COEF_LEN + i * 31 + o;
            else                 p = COEF_LEN + 961 + i * 31 + o;
        }
        s16x8 vr[NR];
        #pragma unroll
        for (int r = 0; r < NR; ++r)
            #pragma unroll
            for (int jj = 0; jj < 8; ++jj) vr[r][jj] = 0;
        #pragma unroll
        for (int jj = 0; jj < 8; ++jj) {
            int ci = q8 * 8 + jj;
            if (p >= 0 && ci < 31) {
                const float* gr = gw + (long)p * 279 + ci * 9;
                #pragma unroll
                for (int r = 0; r < NR; ++r) vr[r][jj] = (short)f2bf(gr[r]);
            }
        }
        #pragma unroll
        for (int r = 0; r < NR; ++r)
            *reinterpret_cast<s16x8*>(bp + (((size_t)i * NR + r) * NFRG + f) * FRAG_U16 + lane * 8) = vr[r];
    } else if (tt < NMAIN + BIAS_ELE) {
        int u = tt - NMAIN;
        int m = u & 15;
        int t2 = u >> 4;
        int f = t2 % NFRG;
        int i = t2 / NFRG;
        int o = (m >> 2) * 8 + f / 3;
        int jslot = (f % 3) * 4 + (m & 3);
        float val = 0.f;
        if (o < OUT_CH && jslot < 10) {
            int p;
            if (jslot < 8)       p = i * 248 + o * 8 + jslot;
            else if (jslot == 8) p = COEF_LEN + i * 31 + o;
            else                 p = COEF_LEN + 961 + i * 31 + o;
            val = gb[p];
        }
        bias_pk[u] = val;
    }
}

// ---------------------------------------------------------------------------
// Fused conv-GEMM + KAN epilogue. A-fragments stream GLOBAL -> VGPR (each
// frag consumed by exactly one wave: WM=8, WP=1 -> zero duplication, no LDS
// round-trip, compiler-managed register deps = structurally race-free).
// LDS holds only the read-only x slab + bias; ONE __syncthreads total.
// Grid 256 = 128 rows x 2 chunk-groups, 1 block/CU.
// __launch_bounds__(512,1): VGPR cap 512 (NOT the 128 cap that (512,2)
// empirically imposes -> R10's 110MB spill + L2 thrash). Live set ~190 regs
// -> no spill, 2 waves/SIMD occupancy (the design point).
// Per step: prefetch pa[(r+1)&1] (static idx, unrolled) -> 8 pbv ds_reads ->
// 24 MFMA. LDS traffic = B only (64 KB/step). acc[3][8]=96 VGPR.
// Output: cg0 -> out, cg1 -> ws partial (+reduce); chained fallback if ws small.
// ---------------------------------------------------------------------------
__global__ void __launch_bounds__(512, 1)
main_kernel(const float* __restrict__ x, const unsigned short* __restrict__ bp3,
            const float* __restrict__ bias_pk, float* __restrict__ dst0,
            float* __restrict__ dst1, int two_cg, int c0_in, int nc_in, int add_in) {
    __shared__ unsigned short slab[3 * 130 * SLAB_STRIDE];   // 31200 B
    __shared__ float biasl[16 * NFRG * 16];                  // 24576 B

    const int tid = threadIdx.x;
    const int bid = blockIdx.x;
    int row, c0, nc, addf;
    float* dst;
    if (two_cg) {
        int cg = bid & 1;
        row = bid >> 1;
        c0 = cg ? 16 : 0;
        nc = cg ? 15 : 16;
        dst = cg ? dst1 : dst0;
        addf = 0;
    } else {
        row = bid; c0 = c0_in; nc = nc_in; dst = dst0; addf = add_in;
    }

    // slab: rows row-1..row+1, cols -1..128, ALL 40 slots written (31..39 = 0)
    for (int idx = tid; idx < 3 * 130 * SLAB_STRIDE; idx += 512) {
        int slot = idx % SLAB_STRIDE;
        int t = idx / SLAB_STRIDE;
        int cc = t % 130;
        int rr = t / 130;
        int hh = row - 1 + rr, ww = cc - 1;
        float v = 0.f;
        if (slot < 31 && (unsigned)hh < 128u && (unsigned)ww < 128u)
            v = x[slot * NPIX + hh * 128 + ww];
        slab[(rr * 130 + cc) * SLAB_STRIDE + slot] = f2bf(v);
    }
    // bias slice -> LDS
    for (int idx = tid; idx < nc * NFRG * 16; idx += 512)
        biasl[idx] = bias_pk[(size_t)c0 * NFRG * 16 + idx];
    __syncthreads();
    // ---- no further barriers; all cross-thread data is read-only below ----

    const int lane = tid & 63;
    const int wave = tid >> 6;       // 0..7: frags [3*wave, 3*wave+3)
    const int q = lane >> 4;
    const int pix16 = lane & 15;

    int sa[8];
    #pragma unroll
    for (int pg = 0; pg < 8; ++pg)
        sa[pg] = (pg * 16 + pix16) * (SLAB_STRIDE * 2) + q * 16;   // byte offsets

    float oreg[8];
    #pragma unroll
    for (int pg = 0; pg < 8; ++pg) oreg[pg] = 0.f;

    #pragma unroll 1
    for (int k = 0; k < nc; ++k) {
        const int ic = c0 + k;
        // per-chunk A base: frag fl at step r lives at aw + (r*NFRG + fl)*FRAG_U16
        const unsigned short* aw = bp3 + ((size_t)ic * NR * NFRG + wave * 3) * FRAG_U16 + lane * 8;

        // issue r=0 A loads first (fly under acc-init ds_reads)
        s16x8 pa[2][3];
        #pragma unroll
        for (int fl = 0; fl < 3; ++fl)
            pa[0][fl] = *reinterpret_cast<const s16x8*>(aw + fl * FRAG_U16);

        // acc init = bias (LDS broadcast; bias added once, by owning chunk)
        f32x4 acc[3][8];
        const float* bl = biasl + (k * NFRG + wave * 3) * 16 + q * 4;
        #pragma unroll
        for (int fl = 0; fl < 3; ++fl) {
            f32x4 b = *reinterpret_cast<const f32x4*>(bl + fl * 16);
            #pragma unroll
            for (int pg = 0; pg < 8; ++pg) acc[fl][pg] = b;
        }

        #pragma unroll
        for (int r = 0; r < NR; ++r) {
            if (r + 1 < NR) {    // reg-dbuf prefetch; static index (r unrolled)
                #pragma unroll
                for (int fl = 0; fl < 3; ++fl)
                    pa[(r + 1) & 1][fl] = *reinterpret_cast<const s16x8*>(
                        aw + ((r + 1) * NFRG + fl) * FRAG_U16);
            }
            const int roff = ((r / 3) * 130 + (r % 3)) * (SLAB_STRIDE * 2);
            s16x8 pbv[8];
            #pragma unroll
            for (int pg = 0; pg < 8; ++pg)
                pbv[pg] = *reinterpret_cast<const s16x8*>(((const char*)slab) + sa[pg] + roff);

            __builtin_amdgcn_s_setprio(1);
            #pragma unroll
            for (int fl = 0; fl < 3; ++fl)
                #pragma unroll
                for (int pg = 0; pg < 8; ++pg)
                    acc[fl][pg] = __builtin_amdgcn_mfma_f32_16x16x32_bf16(
                        pa[r & 1][fl], pbv[pg], acc[fl][pg], 0, 0, 0);
            __builtin_amdgcn_s_setprio(0);
        }

        // lane-local epilogue: closed-form cubic B-spline + silu residual.
        // lane owns o = q*8 + wave; jslot = fl*4 + reg (fl0-1 coef, fl2 univ/res)
        #pragma unroll
        for (int pg = 0; pg < 8; ++pg) {
            const int wcol = pg * 16 + pix16;
            unsigned short sv = slab[(130 + wcol + 1) * SLAB_STRIDE + ic];
            float xv = __uint_as_float((unsigned)sv << 16);
            float u5 = (xv + 1.0f) * 2.5f;
            float cf = fminf(fmaxf(floorf(u5), 0.f), 4.f);
            int ccb = (int)cf;
            float t = u5 - cf;
            float omt = 1.f - t;
            float t2v = t * t, t3v = t2v * t;
            float bw0 = omt * omt * omt * (1.f / 6.f);
            float bw1 = (3.f * t3v - 6.f * t2v + 4.f) * (1.f / 6.f);
            float bw2 = (-3.f * t3v + 3.f * t2v + 3.f * t + 1.f) * (1.f / 6.f);
            float bw3 = t3v * (1.f / 6.f);
            float sl = xv / (1.f + __expf(-xv));
            float w[8];
            #pragma unroll
            for (int j = 0; j < 8; ++j) {
                float wv = 0.f;
                wv = (j == ccb)     ? bw0 : wv;
                wv = (j == ccb + 1) ? bw1 : wv;
                wv = (j == ccb + 2) ? bw2 : wv;
                wv = (j == ccb + 3) ? bw3 : wv;
                w[j] = wv;
            }
            float sp = 0.f;
            #pragma unroll
            for (int j = 0; j < 8; ++j)
                sp = fmaf(w[j], acc[j >> 2][pg][j & 3], sp);
            oreg[pg] += acc[2][pg][0] * sp + sl * acc[2][pg][1];
        }
    }

    // write: lane's single output channel o = q*8 + wave (o==31 is pad -> skip)
    const int o = q * 8 + wave;
    if (o < OUT_CH) {
        #pragma unroll
        for (int pg = 0; pg < 8; ++pg) {
            size_t gi = (size_t)o * NPIX + row * 128 + pg * 16 + pix16;
            if (addf) dst[gi] += oreg[pg];
            else      dst[gi]  = oreg[pg];
        }
    }
}

__global__ void reduce_kernel(const float* __restrict__ p1, float* __restrict__ out) {
    int e = blockIdx.x * 256 + threadIdx.x;
    if (e < OUT_CH * NPIX) out[e] += p1[e];
}

extern "C" void kernel_launch(void* const* d_in, const int* in_sizes, int n_in,
                              void* d_out, int out_size, void* d_ws, size_t ws_size,
                              hipStream_t stream) {
    const float* x  = (const float*)d_in[0];   // (1,31,128,128)
    const float* gw = (const float*)d_in[1];   // (9610,31,3,3)
    const float* gb = (const float*)d_in[2];   // (9610,)
    float* outp = (float*)d_out;               // (1,31,128,128)
    unsigned short* bpack = (unsigned short*)d_ws;          // 6,856,704 B
    float* bias_pk = (float*)((char*)d_ws + BP3_B);         // + 47,616 B
    float* p1      = (float*)((char*)d_ws + BP3_B + (size_t)BIAS_ELE * 4);

    const int NMAIN = CHUNKS * NFRG * 64;                   // 47616
    int pack_blocks = (NMAIN + BIAS_ELE + 255) / 256;       // 233
    pack_kernel<<<pack_blocks, 256, 0, stream>>>(gw, gb, bpack, bias_pk);

    if (ws_size >= WS_NEED) {
        // single dispatch, both chunk-groups (cg0 -> out, cg1 -> partial), then add
        main_kernel<<<256, 512, 0, stream>>>(x, bpack, bias_pk, outp, p1, 1, 0, 0, 0);
        reduce_kernel<<<(OUT_CH * NPIX + 255) / 256, 256, 0, stream>>>(p1, outp);
    } else {
        // chained fallback: two sequential half-grid dispatches through d_out
        main_kernel<<<128, 512, 0, stream>>>(x, bpack, bias_pk, outp, nullptr, 0, 0, 16, 0);
        main_kernel<<<128, 512, 0, stream>>>(x, bpack, bias_pk, outp, nullptr, 0, 16, 15, 1);
    }
}

// Round 12
// 171.994 us; speedup vs baseline: 1.6599x; 1.6018x over previous
//
#include <hip/hip_runtime.h>
#include <hip/hip_bf16.h>

// ---- problem constants ----
#define OUT_CH   31
#define COEF_LEN 7688                 // 31*31*8
#define NPIX     16384                // 128*128
#define CHUNKS   31                   // KAN input channels (independent param groups)
#define NFRG     24                   // param fragments per chunk (384 padded M rows)
#define NR       9                    // K-steps: r = ky*3+kx; k-in-step = conv channel ci
#define FRAG_U16 512                  // u16 per fragment (64 lanes x 8)
#define BP3_B    ((size_t)CHUNKS*NR*NFRG*FRAG_U16*2)   // 6,856,704
#define BIAS_ELE (CHUNKS*NFRG*16)     // 11904 f32
#define P1_B     ((size_t)OUT_CH*NPIX*4)               // 2,031,616
#define WS_NEED  (BP3_B + (size_t)BIAS_ELE*4 + P1_B)   // 8,935,936

#define SLAB_STRIDE 40                // u16 slots per (row,col): 80 B, 16B-aligned

using f32x4 = __attribute__((ext_vector_type(4))) float;
using s16x8 = __attribute__((ext_vector_type(8))) short;

__device__ __forceinline__ unsigned short f2bf(float f) {
    unsigned int u = __float_as_uint(f);
    unsigned int r = (u + 0x7FFFu + ((u >> 16) & 1u)) >> 16;
    return (unsigned short)r;
}

// ---------------------------------------------------------------------------
// Pack gen_w/gen_b into bf16 A-fragment layout + bias table.
//  bp3[i][r][f][lane][8] bf16.  M-row m = lane&15; k-in-step ci = (lane>>4)*8+jj.
//  param identity: o = (m>>2)*8 + f/3, jslot = (f%3)*4 + (m&3)
//    jslot 0..7 = coef j, 8 = univ, 9 = res, 10..11 = zero pad
//  bias_pk[(i*24+f)*16 + m] f32 = gb[p].
// ---------------------------------------------------------------------------
__global__ void pack_kernel(const float* __restrict__ gw, const float* __restrict__ gb,
                            unsigned short* __restrict__ bp, float* __restrict__ bias_pk) {
    const int NMAIN = CHUNKS * NFRG * 64;          // 47616
    int tt = blockIdx.x * 256 + threadIdx.x;
    if (tt < NMAIN) {
        int lane = tt & 63;
        int u = tt >> 6;
        int f = u % NFRG;
        int i = u / NFRG;
        int m = lane & 15, q8 = lane >> 4;
        int o = (m >> 2) * 8 + f / 3;
        int jslot = (f % 3) * 4 + (m & 3);
        int p = -1;
        if (o < OUT_CH && jslot < 10) {
            if (jslot < 8)       p = i * 248 + o * 8 + jslot;
            else if (jslot == 8) p = COEF_LEN + i * 31 + o;
            else                 p = COEF_LEN + 961 + i * 31 + o;
        }
        s16x8 vr[NR];
        #pragma unroll
        for (int r = 0; r < NR; ++r)
            #pragma unroll
            for (int jj = 0; jj < 8; ++jj) vr[r][jj] = 0;
        #pragma unroll
        for (int jj = 0; jj < 8; ++jj) {
            int ci = q8 * 8 + jj;
            if (p >= 0 && ci < 31) {
                const float* gr = gw + (long)p * 279 + ci * 9;
                #pragma unroll
                for (int r = 0; r < NR; ++r) vr[r][jj] = (short)f2bf(gr[r]);
            }
        }
        #pragma unroll
        for (int r = 0; r < NR; ++r)
            *reinterpret_cast<s16x8*>(bp + (((size_t)i * NR + r) * NFRG + f) * FRAG_U16 + lane * 8) = vr[r];
    } else if (tt < NMAIN + BIAS_ELE) {
        int u = tt - NMAIN;
        int m = u & 15;
        int t2 = u >> 4;
        int f = t2 % NFRG;
        int i = t2 / NFRG;
        int o = (m >> 2) * 8 + f / 3;
        int jslot = (f % 3) * 4 + (m & 3);
        float val = 0.f;
        if (o < OUT_CH && jslot < 10) {
            int p;
            if (jslot < 8)       p = i * 248 + o * 8 + jslot;
            else if (jslot == 8) p = COEF_LEN + i * 31 + o;
            else                 p = COEF_LEN + 961 + i * 31 + o;
            val = gb[p];
        }
        bias_pk[u] = val;
    }
}

// ---------------------------------------------------------------------------
// Fused conv-GEMM + KAN epilogue. A-fragments stream GLOBAL -> VGPR (each
// frag consumed by exactly one wave -> zero duplication, no LDS round-trip,
// register deps = structurally race-free). LDS: read-only x slab + bias only;
// ONE __syncthreads total.
// 256-THREAD BLOCKS (4 waves = 1 wave/SIMD min) -> __launch_bounds__(256,1)
// gives a 256-VGPR cap; live set ~190 fits -> NO spill (the R10/R11 killer:
// 512-thr blocks empirically cap at 128 regs -> 110MB scratch -> L2/L3
// thrash -> 845MB HBM A-stream).
// Grid 512 = 128 rows x 2 chunk-groups x 2 frag-halves; 2 blocks/CU
// (8 waves/CU, two independent blocks interleave -> no lockstep).
// Wave w owns frags fi = fh*4+w (3 frags) x all 128 px; acc[3][8]=96 VGPR.
// Output: cg0 -> out, cg1 -> ws partial (+reduce); chained fallback if ws small.
// ---------------------------------------------------------------------------
__global__ void __launch_bounds__(256, 1)
main_kernel(const float* __restrict__ x, const unsigned short* __restrict__ bp3,
            const float* __restrict__ bias_pk, float* __restrict__ dst0,
            float* __restrict__ dst1, int two_cg, int c0_in, int nc_in, int add_in) {
    __shared__ unsigned short slab[3 * 130 * SLAB_STRIDE];   // 31200 B
    __shared__ float biasl[16 * NFRG * 16];                  // 24576 B

    const int tid = threadIdx.x;
    const int bid = blockIdx.x;
    int row, c0, nc, addf, fh;
    float* dst;
    if (two_cg) {
        row = bid >> 2;
        int cg = (bid >> 1) & 1;
        fh = bid & 1;
        c0 = cg ? 16 : 0;
        nc = cg ? 15 : 16;
        dst = cg ? dst1 : dst0;
        addf = 0;
    } else {
        row = bid >> 1; fh = bid & 1;
        c0 = c0_in; nc = nc_in; dst = dst0; addf = add_in;
    }

    // slab: rows row-1..row+1, cols -1..128, ALL 40 slots written (31..39 = 0)
    for (int idx = tid; idx < 3 * 130 * SLAB_STRIDE; idx += 256) {
        int slot = idx % SLAB_STRIDE;
        int t = idx / SLAB_STRIDE;
        int cc = t % 130;
        int rr = t / 130;
        int hh = row - 1 + rr, ww = cc - 1;
        float v = 0.f;
        if (slot < 31 && (unsigned)hh < 128u && (unsigned)ww < 128u)
            v = x[slot * NPIX + hh * 128 + ww];
        slab[(rr * 130 + cc) * SLAB_STRIDE + slot] = f2bf(v);
    }
    // bias slice -> LDS
    for (int idx = tid; idx < nc * NFRG * 16; idx += 256)
        biasl[idx] = bias_pk[(size_t)c0 * NFRG * 16 + idx];
    __syncthreads();
    // ---- no further barriers; all cross-thread data is read-only below ----

    const int lane = tid & 63;
    const int fi = fh * 4 + (tid >> 6);   // 0..7: this wave's frag triple
    const int q = lane >> 4;
    const int pix16 = lane & 15;

    int sa[8];
    #pragma unroll
    for (int pg = 0; pg < 8; ++pg)
        sa[pg] = (pg * 16 + pix16) * (SLAB_STRIDE * 2) + q * 16;   // byte offsets

    float oreg[8];
    #pragma unroll
    for (int pg = 0; pg < 8; ++pg) oreg[pg] = 0.f;

    #pragma unroll 1
    for (int k = 0; k < nc; ++k) {
        const int ic = c0 + k;
        // per-chunk A base: frag fl at step r lives at aw + (r*NFRG + fl)*FRAG_U16
        const unsigned short* aw = bp3 + ((size_t)ic * NR * NFRG + fi * 3) * FRAG_U16 + lane * 8;

        // issue r=0 A loads first (fly under acc-init ds_reads)
        s16x8 pa[2][3];
        #pragma unroll
        for (int fl = 0; fl < 3; ++fl)
            pa[0][fl] = *reinterpret_cast<const s16x8*>(aw + fl * FRAG_U16);

        // acc init = bias (LDS broadcast; bias added once, by owning chunk)
        f32x4 acc[3][8];
        const float* bl = biasl + (k * NFRG + fi * 3) * 16 + q * 4;
        #pragma unroll
        for (int fl = 0; fl < 3; ++fl) {
            f32x4 b = *reinterpret_cast<const f32x4*>(bl + fl * 16);
            #pragma unroll
            for (int pg = 0; pg < 8; ++pg) acc[fl][pg] = b;
        }

        #pragma unroll
        for (int r = 0; r < NR; ++r) {
            if (r + 1 < NR) {    // reg-dbuf prefetch; static index (r unrolled)
                #pragma unroll
                for (int fl = 0; fl < 3; ++fl)
                    pa[(r + 1) & 1][fl] = *reinterpret_cast<const s16x8*>(
                        aw + ((r + 1) * NFRG + fl) * FRAG_U16);
            }
            const int roff = ((r / 3) * 130 + (r % 3)) * (SLAB_STRIDE * 2);
            s16x8 pbv[8];
            #pragma unroll
            for (int pg = 0; pg < 8; ++pg)
                pbv[pg] = *reinterpret_cast<const s16x8*>(((const char*)slab) + sa[pg] + roff);

            __builtin_amdgcn_s_setprio(1);
            #pragma unroll
            for (int fl = 0; fl < 3; ++fl)
                #pragma unroll
                for (int pg = 0; pg < 8; ++pg)
                    acc[fl][pg] = __builtin_amdgcn_mfma_f32_16x16x32_bf16(
                        pa[r & 1][fl], pbv[pg], acc[fl][pg], 0, 0, 0);
            __builtin_amdgcn_s_setprio(0);
        }

        // lane-local epilogue: closed-form cubic B-spline + silu residual.
        // lane owns o = q*8 + fi; jslot = fl*4 + reg (fl0-1 coef, fl2 univ/res)
        #pragma unroll
        for (int pg = 0; pg < 8; ++pg) {
            const int wcol = pg * 16 + pix16;
            unsigned short sv = slab[(130 + wcol + 1) * SLAB_STRIDE + ic];
            float xv = __uint_as_float((unsigned)sv << 16);
            float u5 = (xv + 1.0f) * 2.5f;
            float cf = fminf(fmaxf(floorf(u5), 0.f), 4.f);
            int ccb = (int)cf;
            float t = u5 - cf;
            float omt = 1.f - t;
            float t2v = t * t, t3v = t2v * t;
            float bw0 = omt * omt * omt * (1.f / 6.f);
            float bw1 = (3.f * t3v - 6.f * t2v + 4.f) * (1.f / 6.f);
            float bw2 = (-3.f * t3v + 3.f * t2v + 3.f * t + 1.f) * (1.f / 6.f);
            float bw3 = t3v * (1.f / 6.f);
            float sl = xv / (1.f + __expf(-xv));
            float w[8];
            #pragma unroll
            for (int j = 0; j < 8; ++j) {
                float wv = 0.f;
                wv = (j == ccb)     ? bw0 : wv;
                wv = (j == ccb + 1) ? bw1 : wv;
                wv = (j == ccb + 2) ? bw2 : wv;
                wv = (j == ccb + 3) ? bw3 : wv;
                w[j] = wv;
            }
            float sp = 0.f;
            #pragma unroll
            for (int j = 0; j < 8; ++j)
                sp = fmaf(w[j], acc[j >> 2][pg][j & 3], sp);
            oreg[pg] += acc[2][pg][0] * sp + sl * acc[2][pg][1];
        }
    }

    // write: lane's single output channel o = q*8 + fi (o==31 is pad -> skip)
    const int o = q * 8 + fi;
    if (o < OUT_CH) {
        #pragma unroll
        for (int pg = 0; pg < 8; ++pg) {
            size_t gi = (size_t)o * NPIX + row * 128 + pg * 16 + pix16;
            if (addf) dst[gi] += oreg[pg];
            else      dst[gi]  = oreg[pg];
        }
    }
}

__global__ void reduce_kernel(const float* __restrict__ p1, float* __restrict__ out) {
    int e = blockIdx.x * 256 + threadIdx.x;
    if (e < OUT_CH * NPIX) out[e] += p1[e];
}

extern "C" void kernel_launch(void* const* d_in, const int* in_sizes, int n_in,
                              void* d_out, int out_size, void* d_ws, size_t ws_size,
                              hipStream_t stream) {
    const float* x  = (const float*)d_in[0];   // (1,31,128,128)
    const float* gw = (const float*)d_in[1];   // (9610,31,3,3)
    const float* gb = (const float*)d_in[2];   // (9610,)
    float* outp = (float*)d_out;               // (1,31,128,128)
    unsigned short* bpack = (unsigned short*)d_ws;          // 6,856,704 B
    float* bias_pk = (float*)((char*)d_ws + BP3_B);         // + 47,616 B
    float* p1      = (float*)((char*)d_ws + BP3_B + (size_t)BIAS_ELE * 4);

    const int NMAIN = CHUNKS * NFRG * 64;                   // 47616
    int pack_blocks = (NMAIN + BIAS_ELE + 255) / 256;       // 233
    pack_kernel<<<pack_blocks, 256, 0, stream>>>(gw, gb, bpack, bias_pk);

    if (ws_size >= WS_NEED) {
        // single dispatch: 128 rows x 2 cg x 2 frag-halves; cg0 -> out, cg1 -> p1
        main_kernel<<<512, 256, 0, stream>>>(x, bpack, bias_pk, outp, p1, 1, 0, 0, 0);
        reduce_kernel<<<(OUT_CH * NPIX + 255) / 256, 256, 0, stream>>>(p1, outp);
    } else {
        // chained fallback: two sequential dispatches (128 rows x 2 fh each)
        main_kernel<<<256, 256, 0, stream>>>(x, bpack, bias_pk, outp, nullptr, 0, 0, 16, 0);
        main_kernel<<<256, 256, 0, stream>>>(x, bpack, bias_pk, outp, nullptr, 0, 16, 15, 1);
    }
}

// Round 13
// 135.657 us; speedup vs baseline: 2.1045x; 1.2679x over previous
//
#include <hip/hip_runtime.h>
#include <hip/hip_bf16.h>

// ---- problem constants ----
#define OUT_CH   31
#define COEF_LEN 7688                 // 31*31*8
#define NPIX     16384                // 128*128
#define CHUNKS   31                   // KAN input channels (independent param groups)
#define NFRG     24                   // param fragments per chunk (384 padded M rows)
#define NR       9                    // K-steps: r = ky*3+kx; k-in-step = conv channel ci
#define FRAG_U16 512                  // u16 per fragment (64 lanes x 8)
#define BP3_B    ((size_t)CHUNKS*NR*NFRG*FRAG_U16*2)   // 6,856,704
#define P1_B     ((size_t)OUT_CH*NPIX*4)               // 2,031,616
#define WS_NEED  (BP3_B + P1_B)                        // 8,888,320

using f32x4 = __attribute__((ext_vector_type(4))) float;
using s16x8 = __attribute__((ext_vector_type(8))) short;

__device__ __forceinline__ unsigned short f2bf(float f) {
    unsigned int u = __float_as_uint(f);
    unsigned int r = (u + 0x7FFFu + ((u >> 16) & 1u)) >> 16;
    return (unsigned short)r;
}

// ---------------------------------------------------------------------------
// Pack gen_w/gen_b into bf16 A-fragment layout. BIAS IS FOLDED INTO THE GEMM:
// the x-slab's channel slot 31 is constant 1.0, and A[ci=31] at r==4 (center
// tap) carries gb[p] -> bias lands in the accumulator exactly once. No bias
// table, zero acc-init.
//  bp3[i][r][f][lane][8] bf16.  M-row m = lane&15; k-in-step ci = (lane>>4)*8+jj.
//  param identity: o = (m>>2)*8 + f/3, jslot = (f%3)*4 + (m&3)
//    jslot 0..7 = coef j, 8 = univ, 9 = res, 10..11 = zero pad
// ---------------------------------------------------------------------------
__global__ void pack_kernel(const float* __restrict__ gw, const float* __restrict__ gb,
                            unsigned short* __restrict__ bp) {
    const int NMAIN = CHUNKS * NFRG * 64;          // 47616
    int tt = blockIdx.x * 256 + threadIdx.x;
    if (tt >= NMAIN) return;
    int lane = tt & 63;
    int u = tt >> 6;
    int f = u % NFRG;
    int i = u / NFRG;
    int m = lane & 15, q8 = lane >> 4;
    int o = (m >> 2) * 8 + f / 3;
    int jslot = (f % 3) * 4 + (m & 3);
    int p = -1;
    if (o < OUT_CH && jslot < 10) {
        if (jslot < 8)       p = i * 248 + o * 8 + jslot;
        else if (jslot == 8) p = COEF_LEN + i * 31 + o;
        else                 p = COEF_LEN + 961 + i * 31 + o;
    }
    s16x8 vr[NR];
    #pragma unroll
    for (int r = 0; r < NR; ++r)
        #pragma unroll
        for (int jj = 0; jj < 8; ++jj) vr[r][jj] = 0;
    #pragma unroll
    for (int jj = 0; jj < 8; ++jj) {
        int ci = q8 * 8 + jj;
        if (p >= 0) {
            if (ci < 31) {
                const float* gr = gw + (long)p * 279 + ci * 9;
                #pragma unroll
                for (int r = 0; r < NR; ++r) vr[r][jj] = (short)f2bf(gr[r]);
            } else {
                vr[4][jj] = (short)f2bf(gb[p]);   // bias channel, center tap only
            }
        }
    }
    #pragma unroll
    for (int r = 0; r < NR; ++r)
        *reinterpret_cast<s16x8*>(bp + (((size_t)i * NR + r) * NFRG + f) * FRAG_U16 + lane * 8) = vr[r];
}

// ---------------------------------------------------------------------------
// Fused conv-GEMM + KAN epilogue. A streams GLOBAL -> VGPR (reg-dbuf, each
// frag read by one wave per block). LDS: read-only 64-px x slab only (15.8 KB);
// ONE __syncthreads. 256-thr blocks, per-wave tile 3 frags x 4 pg:
// live set ~115 regs -> fits the 128-reg cap of __launch_bounds__(256,2)
// -> 4 blocks/CU x 4 waves = 4 waves/SIMD (the R12 fix: 252 regs = 1 wave/SIMD).
// Grid 1024 = 128 rows x 2 col-halves x 2 cg x 2 fh; cg = bid&1 pins one
// 3.46 MB param slice per XCD L2 (<4 MB). Bias via GEMM (slot31=1.0 column).
// Output: cg0 -> out, cg1 -> ws partial (+reduce); chained fallback if ws small.
// ---------------------------------------------------------------------------
__global__ void __launch_bounds__(256, 2)
main_kernel(const float* __restrict__ x, const unsigned short* __restrict__ bp3,
            float* __restrict__ dst0, float* __restrict__ dst1,
            int two_cg, int c0_in, int nc_in, int add_in) {
    __shared__ unsigned short slab[3 * 66 * 40];   // 15840 B
    const int tid = threadIdx.x;
    const int bid = blockIdx.x;
    int row, ch, c0, nc, addf, fh;
    float* dst;
    if (two_cg) {
        int cg = bid & 1;          // cg pinned per XCD (bid%8 parity)
        fh = (bid >> 1) & 1;
        ch = (bid >> 2) & 1;
        row = bid >> 3;
        c0 = cg ? 16 : 0;
        nc = cg ? 15 : 16;
        dst = cg ? dst1 : dst0;
        addf = 0;
    } else {
        fh = bid & 1; ch = (bid >> 1) & 1; row = bid >> 2;
        c0 = c0_in; nc = nc_in; dst = dst0; addf = add_in;
    }

    // slab: rows row-1..row+1, cols ch*64-1 .. ch*64+64; slot31 = 1.0 (bias col)
    for (int idx = tid; idx < 3 * 66 * 40; idx += 256) {
        int slot = idx % 40;
        int t = idx / 40;
        int cc = t % 66;
        int rr = t / 66;
        int hh = row - 1 + rr, ww = ch * 64 - 1 + cc;
        unsigned short v = 0;
        if (slot < 31) {
            if ((unsigned)hh < 128u && (unsigned)ww < 128u)
                v = f2bf(x[slot * NPIX + hh * 128 + ww]);
        } else if (slot == 31) {
            v = 0x3F80;   // 1.0 bf16
        }
        slab[(rr * 66 + cc) * 40 + slot] = v;
    }
    __syncthreads();
    // ---- no further barriers; slab is read-only below ----

    const int lane = tid & 63;
    const int fi = fh * 4 + (tid >> 6);   // 0..7: this wave's frag triple
    const int q = lane >> 4;
    const int pix16 = lane & 15;
    const char* slabb = (const char*)slab;

    int sa[4];
    #pragma unroll
    for (int pg = 0; pg < 4; ++pg)
        sa[pg] = (pg * 16 + pix16) * 80 + q * 16;   // byte offsets (+roff per step)

    float oreg[4] = {0.f, 0.f, 0.f, 0.f};

    #pragma unroll 1
    for (int k = 0; k < nc; ++k) {
        const int ic = c0 + k;
        const unsigned short* aw = bp3 + ((size_t)ic * NR * NFRG + fi * 3) * FRAG_U16 + lane * 8;

        s16x8 pa[2][3];
        #pragma unroll
        for (int fl = 0; fl < 3; ++fl)
            pa[0][fl] = *reinterpret_cast<const s16x8*>(aw + fl * FRAG_U16);

        f32x4 acc[3][4];
        #pragma unroll
        for (int fl = 0; fl < 3; ++fl)
            #pragma unroll
            for (int pg = 0; pg < 4; ++pg)
                acc[fl][pg] = (f32x4){0.f, 0.f, 0.f, 0.f};   // bias comes via GEMM

        #pragma unroll
        for (int r = 0; r < NR; ++r) {
            if (r + 1 < NR) {    // reg-dbuf prefetch; static index (r unrolled)
                #pragma unroll
                for (int fl = 0; fl < 3; ++fl)
                    pa[(r + 1) & 1][fl] = *reinterpret_cast<const s16x8*>(
                        aw + ((r + 1) * NFRG + fl) * FRAG_U16);
            }
            const int roff = ((r / 3) * 66 + (r % 3)) * 80;
            s16x8 pbv[4];
            #pragma unroll
            for (int pg = 0; pg < 4; ++pg)
                pbv[pg] = *reinterpret_cast<const s16x8*>(slabb + sa[pg] + roff);

            __builtin_amdgcn_s_setprio(1);
            #pragma unroll
            for (int fl = 0; fl < 3; ++fl)
                #pragma unroll
                for (int pg = 0; pg < 4; ++pg)
                    acc[fl][pg] = __builtin_amdgcn_mfma_f32_16x16x32_bf16(
                        pa[r & 1][fl], pbv[pg], acc[fl][pg], 0, 0, 0);
            __builtin_amdgcn_s_setprio(0);
        }

        // lane-local epilogue: closed-form cubic B-spline + silu residual.
        // lane owns o = q*8 + fi; jslot = fl*4 + reg (fl0-1 coef, fl2 univ/res)
        #pragma unroll
        for (int pg = 0; pg < 4; ++pg) {
            const int pl = pg * 16 + pix16;
            unsigned short sv = slab[(66 + pl + 1) * 40 + ic];   // center px, ch ic
            float xv = __uint_as_float((unsigned)sv << 16);
            float u5 = (xv + 1.0f) * 2.5f;
            float cf = fminf(fmaxf(floorf(u5), 0.f), 4.f);
            int ccb = (int)cf;
            float t = u5 - cf;
            float omt = 1.f - t;
            float t2v = t * t, t3v = t2v * t;
            float bw0 = omt * omt * omt * (1.f / 6.f);
            float bw1 = (3.f * t3v - 6.f * t2v + 4.f) * (1.f / 6.f);
            float bw2 = (-3.f * t3v + 3.f * t2v + 3.f * t + 1.f) * (1.f / 6.f);
            float bw3 = t3v * (1.f / 6.f);
            float sl = xv / (1.f + __expf(-xv));
            float w[8];
            #pragma unroll
            for (int j = 0; j < 8; ++j) {
                float wv = 0.f;
                wv = (j == ccb)     ? bw0 : wv;
                wv = (j == ccb + 1) ? bw1 : wv;
                wv = (j == ccb + 2) ? bw2 : wv;
                wv = (j == ccb + 3) ? bw3 : wv;
                w[j] = wv;
            }
            float sp = 0.f;
            #pragma unroll
            for (int j = 0; j < 8; ++j)
                sp = fmaf(w[j], acc[j >> 2][pg][j & 3], sp);
            oreg[pg] += acc[2][pg][0] * sp + sl * acc[2][pg][1];
        }
    }

    // write: lane's single output channel o = q*8 + fi (o==31 is pad -> skip)
    const int o = q * 8 + fi;
    if (o < OUT_CH) {
        #pragma unroll
        for (int pg = 0; pg < 4; ++pg) {
            size_t gi = (size_t)o * NPIX + row * 128 + ch * 64 + pg * 16 + pix16;
            if (addf) dst[gi] += oreg[pg];
            else      dst[gi]  = oreg[pg];
        }
    }
}

__global__ void reduce_kernel(const float* __restrict__ p1, float* __restrict__ out) {
    int e = blockIdx.x * 256 + threadIdx.x;
    if (e < OUT_CH * NPIX) out[e] += p1[e];
}

extern "C" void kernel_launch(void* const* d_in, const int* in_sizes, int n_in,
                              void* d_out, int out_size, void* d_ws, size_t ws_size,
                              hipStream_t stream) {
    const float* x  = (const float*)d_in[0];   // (1,31,128,128)
    const float* gw = (const float*)d_in[1];   // (9610,31,3,3)
    const float* gb = (const float*)d_in[2];   // (9610,)
    float* outp = (float*)d_out;               // (1,31,128,128)
    unsigned short* bpack = (unsigned short*)d_ws;          // 6,856,704 B
    float* p1 = (float*)((char*)d_ws + BP3_B);

    const int NMAIN = CHUNKS * NFRG * 64;                   // 47616
    pack_kernel<<<(NMAIN + 255) / 256, 256, 0, stream>>>(gw, gb, bpack);

    if (ws_size >= WS_NEED) {
        // 1024 blocks = 128 rows x 2 col-halves x 2 cg x 2 fh; cg0 -> out, cg1 -> p1
        main_kernel<<<1024, 256, 0, stream>>>(x, bpack, outp, p1, 1, 0, 0, 0);
        reduce_kernel<<<(OUT_CH * NPIX + 255) / 256, 256, 0, stream>>>(p1, outp);
    } else {
        // chained fallback: two sequential dispatches (512 blocks each) through d_out
        main_kernel<<<512, 256, 0, stream>>>(x, bpack, outp, nullptr, 0, 0, 16, 0);
        main_kernel<<<512, 256, 0, stream>>>(x, bpack, outp, nullptr, 0, 16, 15, 1);
    }
}

// Round 14
// 114.468 us; speedup vs baseline: 2.4940x; 1.1851x over previous
//
#include <hip/hip_runtime.h>
#include <hip/hip_bf16.h>

// ---- problem constants ----
#define OUT_CH   31
#define COEF_LEN 7688                 // 31*31*8
#define NPIX     16384                // 128*128
#define CHUNKS   31                   // KAN input channels (independent param groups)
#define NFRG     24                   // param fragments per chunk (384 padded M rows)
#define NR       9                    // K-steps: r = ky*3+kx; k-in-step = conv channel ci
#define FRAG_U16 512                  // u16 per fragment (64 lanes x 8)
#define BP3_B    ((size_t)CHUNKS*NR*NFRG*FRAG_U16*2)   // 6,856,704
#define P1_B     ((size_t)OUT_CH*NPIX*4)               // 2,031,616
#define WS_NEED  (BP3_B + P1_B)                        // 8,888,320

using f32x4 = __attribute__((ext_vector_type(4))) float;
using s16x8 = __attribute__((ext_vector_type(8))) short;

__device__ __forceinline__ unsigned short f2bf(float f) {
    unsigned int u = __float_as_uint(f);
    unsigned int r = (u + 0x7FFFu + ((u >> 16) & 1u)) >> 16;
    return (unsigned short)r;
}

// ---------------------------------------------------------------------------
// Pack gen_w/gen_b into bf16 A-fragment layout. Bias folded into the GEMM:
// slab channel slot 31 is constant 1.0; A[ci=31] at r==4 carries gb[p].
//  bp3[i][r][f][lane][8] bf16.  M-row m = lane&15; k-in-step ci = (lane>>4)*8+jj.
//  param identity: o = (m>>2)*8 + f/3, jslot = (f%3)*4 + (m&3)
//    jslot 0..7 = coef j, 8 = univ, 9 = res, 10..11 = zero pad
// ---------------------------------------------------------------------------
__global__ void pack_kernel(const float* __restrict__ gw, const float* __restrict__ gb,
                            unsigned short* __restrict__ bp) {
    const int NMAIN = CHUNKS * NFRG * 64;          // 47616
    int tt = blockIdx.x * 256 + threadIdx.x;
    if (tt >= NMAIN) return;
    int lane = tt & 63;
    int u = tt >> 6;
    int f = u % NFRG;
    int i = u / NFRG;
    int m = lane & 15, q8 = lane >> 4;
    int o = (m >> 2) * 8 + f / 3;
    int jslot = (f % 3) * 4 + (m & 3);
    int p = -1;
    if (o < OUT_CH && jslot < 10) {
        if (jslot < 8)       p = i * 248 + o * 8 + jslot;
        else if (jslot == 8) p = COEF_LEN + i * 31 + o;
        else                 p = COEF_LEN + 961 + i * 31 + o;
    }
    s16x8 vr[NR];
    #pragma unroll
    for (int r = 0; r < NR; ++r)
        #pragma unroll
        for (int jj = 0; jj < 8; ++jj) vr[r][jj] = 0;
    #pragma unroll
    for (int jj = 0; jj < 8; ++jj) {
        int ci = q8 * 8 + jj;
        if (p >= 0) {
            if (ci < 31) {
                const float* gr = gw + (long)p * 279 + ci * 9;
                #pragma unroll
                for (int r = 0; r < NR; ++r) vr[r][jj] = (short)f2bf(gr[r]);
            } else {
                vr[4][jj] = (short)f2bf(gb[p]);   // bias channel, center tap only
            }
        }
    }
    #pragma unroll
    for (int r = 0; r < NR; ++r)
        *reinterpret_cast<s16x8*>(bp + (((size_t)i * NR + r) * NFRG + f) * FRAG_U16 + lane * 8) = vr[r];
}

// ---------------------------------------------------------------------------
// Fused conv-GEMM + KAN epilogue. A streams GLOBAL -> VGPR (reg-dbuf; each
// frag read by exactly one wave per block). LDS: read-only 64-px x slab only;
// ONE __syncthreads. 512-thr blocks = 8 fi-waves (full 24 frags/block), each
// wave 3 frags x 4 pg: live ~115 regs -> fits the 512-thr ~128-reg behavior
// with NO spill, and big blocks maximize waves/CU (scheduler co-resides only
// ~1.6-2 blocks/CU regardless of size: R6/R7/R13 evidence).
// Epilogue: per-pixel spline/silu computed ONCE per pixel (lane owns pixel =
// its lane id), shared via __shfl; coefficient-select tree (4 cmp + 16 sel)
// replaces the 64-op w[8] build. Bias via GEMM (slot31=1.0 column).
// Grid 512 = 128 rows x 2 col-halves x 2 cg; cg = bid&1 pins one 3.46 MB
// param slice per XCD L2. Output: cg0 -> out, cg1 -> ws partial (+reduce).
// ---------------------------------------------------------------------------
__global__ void __launch_bounds__(512, 1)
main_kernel(const float* __restrict__ x, const unsigned short* __restrict__ bp3,
            float* __restrict__ dst0, float* __restrict__ dst1,
            int two_cg, int c0_in, int nc_in, int add_in) {
    __shared__ unsigned short slab[3 * 66 * 40];   // 15840 B
    const int tid = threadIdx.x;
    const int bid = blockIdx.x;
    int row, ch, c0, nc, addf;
    float* dst;
    if (two_cg) {
        int cg = bid & 1;          // XCD = bid%8 -> cg fixed per XCD (L2 pin)
        ch = (bid >> 1) & 1;
        row = bid >> 2;
        c0 = cg ? 16 : 0;
        nc = cg ? 15 : 16;
        dst = cg ? dst1 : dst0;
        addf = 0;
    } else {
        ch = bid & 1; row = bid >> 1;
        c0 = c0_in; nc = nc_in; dst = dst0; addf = add_in;
    }

    // slab: rows row-1..row+1, cols ch*64-1 .. ch*64+64; slot31 = 1.0 (bias col)
    for (int idx = tid; idx < 3 * 66 * 40; idx += 512) {
        int slot = idx % 40;
        int t = idx / 40;
        int cc = t % 66;
        int rr = t / 66;
        int hh = row - 1 + rr, ww = ch * 64 - 1 + cc;
        unsigned short v = 0;
        if (slot < 31) {
            if ((unsigned)hh < 128u && (unsigned)ww < 128u)
                v = f2bf(x[slot * NPIX + hh * 128 + ww]);
        } else if (slot == 31) {
            v = 0x3F80;   // 1.0 bf16
        }
        slab[(rr * 66 + cc) * 40 + slot] = v;
    }
    __syncthreads();
    // ---- no further barriers; slab is read-only below ----

    const int lane = tid & 63;
    const int fi = tid >> 6;              // 0..7: this wave's frag triple
    const int q = lane >> 4;
    const int pix16 = lane & 15;
    const char* slabb = (const char*)slab;

    int sa[4];
    #pragma unroll
    for (int pg = 0; pg < 4; ++pg)
        sa[pg] = (pg * 16 + pix16) * 80 + q * 16;   // byte offsets (+roff per step)

    float oreg[4] = {0.f, 0.f, 0.f, 0.f};

    #pragma unroll 1
    for (int k = 0; k < nc; ++k) {
        const int ic = c0 + k;
        const unsigned short* aw = bp3 + ((size_t)ic * NR * NFRG + fi * 3) * FRAG_U16 + lane * 8;

        s16x8 pa[2][3];
        #pragma unroll
        for (int fl = 0; fl < 3; ++fl)
            pa[0][fl] = *reinterpret_cast<const s16x8*>(aw + fl * FRAG_U16);

        f32x4 acc[3][4];
        #pragma unroll
        for (int fl = 0; fl < 3; ++fl)
            #pragma unroll
            for (int pg = 0; pg < 4; ++pg)
                acc[fl][pg] = (f32x4){0.f, 0.f, 0.f, 0.f};   // bias comes via GEMM

        #pragma unroll
        for (int r = 0; r < NR; ++r) {
            if (r + 1 < NR) {    // reg-dbuf prefetch; static index (r unrolled)
                #pragma unroll
                for (int fl = 0; fl < 3; ++fl)
                    pa[(r + 1) & 1][fl] = *reinterpret_cast<const s16x8*>(
                        aw + ((r + 1) * NFRG + fl) * FRAG_U16);
            }
            const int roff = ((r / 3) * 66 + (r % 3)) * 80;
            s16x8 pbv[4];
            #pragma unroll
            for (int pg = 0; pg < 4; ++pg)
                pbv[pg] = *reinterpret_cast<const s16x8*>(slabb + sa[pg] + roff);

            __builtin_amdgcn_s_setprio(1);
            #pragma unroll
            for (int fl = 0; fl < 3; ++fl)
                #pragma unroll
                for (int pg = 0; pg < 4; ++pg)
                    acc[fl][pg] = __builtin_amdgcn_mfma_f32_16x16x32_bf16(
                        pa[r & 1][fl], pbv[pg], acc[fl][pg], 0, 0, 0);
            __builtin_amdgcn_s_setprio(0);
        }

        // ---- epilogue ----
        // Per-pixel spline/silu computed ONCE: lane owns pixel p_own = lane
        // (= q*16 + pix16), shared to the 4 quartile lanes via __shfl.
        float bw0, bw1, bw2, bw3, cfv, slv;
        {
            unsigned short sv = slab[(66 + lane + 1) * 40 + ic];  // center px=lane
            float xv = __uint_as_float((unsigned)sv << 16);
            float u5 = (xv + 1.0f) * 2.5f;
            cfv = fminf(fmaxf(floorf(u5), 0.f), 4.f);
            float t = u5 - cfv;
            float t2v = t * t, t3v = t2v * t;
            float omt = 1.f - t;
            bw3 = t3v * (1.f / 6.f);
            bw0 = omt * omt * omt * (1.f / 6.f);
            bw1 = 0.5f * t3v - t2v + (2.f / 3.f);
            bw2 = 1.f - bw0 - bw1 - bw3;          // partition of unity
            slv = xv / (1.f + __expf(-xv));
        }

        #pragma unroll
        for (int pg = 0; pg < 4; ++pg) {
            const int src = pg * 16 + pix16;      // lane owning pixel pg*16+pix16
            float b0 = __shfl(bw0, src);
            float b1 = __shfl(bw1, src);
            float b2 = __shfl(bw2, src);
            float b3 = __shfl(bw3, src);
            float cfp = __shfl(cfv, src);
            float slp = __shfl(slv, src);

            // coefficient-select tree: Ci = coef[cc+i], cc = (int)cfp in 0..4
            const float c0v = acc[0][pg][0], c1v = acc[0][pg][1];
            const float c2v = acc[0][pg][2], c3v = acc[0][pg][3];
            const float c4v = acc[1][pg][0], c5v = acc[1][pg][1];
            const float c6v = acc[1][pg][2], c7v = acc[1][pg][3];
            const bool m1 = cfp >= 1.f, m2 = cfp >= 2.f, m3 = cfp >= 3.f, m4 = cfp >= 4.f;
            float C0 = m1 ? c1v : c0v; C0 = m2 ? c2v : C0; C0 = m3 ? c3v : C0; C0 = m4 ? c4v : C0;
            float C1 = m1 ? c2v : c1v; C1 = m2 ? c3v : C1; C1 = m3 ? c4v : C1; C1 = m4 ? c5v : C1;
            float C2 = m1 ? c3v : c2v; C2 = m2 ? c4v : C2; C2 = m3 ? c5v : C2; C2 = m4 ? c6v : C2;
            float C3 = m1 ? c4v : c3v; C3 = m2 ? c5v : C3; C3 = m3 ? c6v : C3; C3 = m4 ? c7v : C3;

            float sp = b0 * C0;
            sp = fmaf(b1, C1, sp);
            sp = fmaf(b2, C2, sp);
            sp = fmaf(b3, C3, sp);
            oreg[pg] = fmaf(acc[2][pg][0], sp, fmaf(slp, acc[2][pg][1], oreg[pg]));
        }
    }

    // write: lane's single output channel o = q*8 + fi (o==31 is pad -> skip)
    const int o = q * 8 + fi;
    if (o < OUT_CH) {
        #pragma unroll
        for (int pg = 0; pg < 4; ++pg) {
            size_t gi = (size_t)o * NPIX + row * 128 + ch * 64 + pg * 16 + pix16;
            if (addf) dst[gi] += oreg[pg];
            else      dst[gi]  = oreg[pg];
        }
    }
}

__global__ void reduce_kernel(const float* __restrict__ p1, float* __restrict__ out) {
    int e = blockIdx.x * 256 + threadIdx.x;
    if (e < OUT_CH * NPIX) out[e] += p1[e];
}

extern "C" void kernel_launch(void* const* d_in, const int* in_sizes, int n_in,
                              void* d_out, int out_size, void* d_ws, size_t ws_size,
                              hipStream_t stream) {
    const float* x  = (const float*)d_in[0];   // (1,31,128,128)
    const float* gw = (const float*)d_in[1];   // (9610,31,3,3)
    const float* gb = (const float*)d_in[2];   // (9610,)
    float* outp = (float*)d_out;               // (1,31,128,128)
    unsigned short* bpack = (unsigned short*)d_ws;          // 6,856,704 B
    float* p1 = (float*)((char*)d_ws + BP3_B);

    const int NMAIN = CHUNKS * NFRG * 64;                   // 47616
    pack_kernel<<<(NMAIN + 255) / 256, 256, 0, stream>>>(gw, gb, bpack);

    if (ws_size >= WS_NEED) {
        // 512 blocks = 128 rows x 2 col-halves x 2 cg; cg0 -> out, cg1 -> p1
        main_kernel<<<512, 512, 0, stream>>>(x, bpack, outp, p1, 1, 0, 0, 0);
        reduce_kernel<<<(OUT_CH * NPIX + 255) / 256, 256, 0, stream>>>(p1, outp);
    } else {
        // chained fallback: two sequential dispatches (256 blocks each) through d_out
        main_kernel<<<256, 512, 0, stream>>>(x, bpack, outp, nullptr, 0, 0, 16, 0);
        main_kernel<<<256, 512, 0, stream>>>(x, bpack, outp, nullptr, 0, 16, 15, 1);
    }
}